// Round 10
// baseline (449.987 us; speedup 1.0000x reference)
//
#include <hip/hip_runtime.h>
#include <math.h>

// Single-head equivalence (4 identical heads; mean over identical outputs = id).
// Round 10: proven r5 loop body (VGPR=64, no spill) + NSPLIT=4 occupancy
// (1024 blocks = 4/CU = 32 waves/CU) + proven r8 fused atomic-ticket merge.
//   prepass:    K,Q -> fp16 planes (Kh row, VT transposed+slot-permuted, Qh row
//               with d0 negated) + dense fp32 K128/Q128 columns.
//   attn_fused: 16 queries/block, 8 waves stream disjoint KV tiles of their
//               KV quarter (no main-loop barriers/LDS). XCD-pinned splits.
//               In-block 8-wave merge + cross-split ticket merge + double
//               Lorentz normalization.
//   Register discipline (r7/r9 lessons): launch_bounds(512,4) -> cap 128,
//   natural alloc 64; NO explicit register double-buffer, NO (512,8) strangle.

typedef __attribute__((ext_vector_type(8))) _Float16 f16x8;
typedef __attribute__((ext_vector_type(8))) short short8;
typedef __attribute__((ext_vector_type(4))) float f32x4;

#define NQ 4096
#define DD 129
#define BM 16
#define NWAVE 8
#define NT 512
#define TILE 32
#define NQG (NQ / BM)                       // 256

// d_ws byte offsets
#define WS_KH   ((size_t)0)                        // NQ*128 fp16 = 1 MB
#define WS_VT   ((size_t)1 << 20)                  // 128*NQ fp16 = 1 MB
#define WS_QH   ((size_t)2 << 20)                  // NQ*128 fp16 = 1 MB
#define WS_K128 ((size_t)3 << 20)                  // NQ fp32 = 16 KB
#define WS_Q128 (((size_t)3 << 20) + (16 << 10))   // NQ fp32 = 16 KB
#define WS_CNT  (((size_t)3 << 20) + (32 << 10))   // NQG ints = 1 KB
#define WS_MLA  (((size_t)3 << 20) + (64 << 10))   // NQG*4*48 f32 = 192 KB
#define WS_OP   ((size_t)4 << 20)                  // NQG*NSPLIT*16*128 f32
#define NEED(nsplit) (WS_OP + (size_t)NQG * (nsplit) * BM * 128 * 4)

__device__ __forceinline__ short f2h_bits(float x) {
  _Float16 h = (_Float16)x;
  return *reinterpret_cast<short*>(&h);
}

#define MF(a, b, cacc) __builtin_amdgcn_mfma_f32_16x16x32_f16(a, b, cacc, 0, 0, 0)

// ---------------- prepass (proven rounds 5-9, unchanged) ---------------------
__global__ __launch_bounds__(256) void prepass(
    const float* __restrict__ Kg, const float* __restrict__ Qg,
    short* __restrict__ Kh, short* __restrict__ Qh, short* __restrict__ VT,
    float* __restrict__ K128, float* __restrict__ Q128)
{
  __shared__ short tile[32][72];
  const int bx  = blockIdx.x;
  const int isQ = blockIdx.y;
  const int jg = bx >> 1, dh = bx & 1;
  const int j0 = jg * 32, d0 = dh * 64;
  const float* src = isQ ? Qg : Kg;
  short* plane = isQ ? Qh : Kh;

  const int t  = threadIdx.x;
  const int r  = t >> 3;
  const int e0 = (t & 7) * 8;

  {
    const float* s = src + (size_t)(j0 + r) * DD + d0 + e0;
    short8 sv;
#pragma unroll
    for (int e = 0; e < 8; ++e) {
      float v = s[e];
      if (isQ && dh == 0 && e0 == 0 && e == 0) v = -v;   // Lorentz time coord
      sv[e] = f2h_bits(v);
    }
    *reinterpret_cast<short8*>(&tile[r][e0]) = sv;
    *reinterpret_cast<short8*>(plane + (size_t)(j0 + r) * 128 + d0 + e0) = sv;
  }
  if (dh == 0 && t < 32) {
    const float v = src[(size_t)(j0 + t) * DD + 128];
    (isQ ? Q128 : K128)[j0 + t] = v;
  }
  if (isQ) return;
  __syncthreads();

  // transposed + k-slot-permuted plane (slot p=8g+e <-> j: e<4->4g+e else 16+4g+e-4)
  {
    const int dl = t >> 2, q8 = t & 3;
    short8 sv;
#pragma unroll
    for (int e = 0; e < 8; ++e) {
      const int j = (e < 4) ? (4 * q8 + e) : (16 + 4 * q8 + (e - 4));
      sv[e] = tile[j][dl];
    }
    *reinterpret_cast<short8*>(VT + (size_t)(d0 + dl) * NQ + j0 + q8 * 8) = sv;
  }
}

// ---------------- fused flash attention + last-block merge -------------------
template <int NSPLIT>
__global__ __launch_bounds__(NT, 4) void attn_fused(
    const short* __restrict__ Qh, const float* __restrict__ Q128,
    const short* __restrict__ Kh, const short* __restrict__ VT,
    const float* __restrict__ K128,
    const float* __restrict__ scale_p, const float* __restrict__ bias_p,
    float* __restrict__ OP, float* __restrict__ MLA, int* __restrict__ cnt,
    float* __restrict__ outg)
{
  constexpr int KVSEG = NQ / NSPLIT;
  constexpr int NSTEP = KVSEG / (NWAVE * TILE);
  constexpr int XPS   = 8 / NSPLIT;          // XCDs per split

  __shared__ float OwS[4][BM * 128];
  __shared__ float mS[NWAVE][BM], lS[NWAVE][BM], aS[NWAVE][BM];
  __shared__ int lastS;

  // XCD-pinned bijection: blocks on one XCD share sp.
  const int bid = blockIdx.x;                // 0..NQG*NSPLIT-1
  const int xcd = bid & 7;
  const int sp  = xcd / XPS;
  const int qg  = (xcd % XPS) * (NQG / XPS) + (bid >> 3);
  const int spBase = sp * KVSEG;

  const int tid  = threadIdx.x;
  const int wid  = tid >> 6;
  const int lane = tid & 63;
  const int g    = lane >> 4;   // 0..3
  const int c    = lane & 15;   // 0..15
  const int row0 = qg * BM;

  const float sA = 2.0f / scale_p[0];
  const float sB = sA + bias_p[0];           // S = dot*sA + sB

  const int qrow = row0 + c;
  f16x8 qf[4];
#pragma unroll
  for (int cc = 0; cc < 4; ++cc)
    qf[cc] = *reinterpret_cast<const f16x8*>(Qh + (size_t)qrow * 128 + 32 * cc + 8 * g);
  const float q128 = Q128[qrow];

  f32x4 accO[8];
#pragma unroll
  for (int i = 0; i < 8; ++i) accO[i] = (f32x4){0.f, 0.f, 0.f, 0.f};
  float m_run = -INFINITY, l_run = 0.f, a128 = 0.f;

  for (int t = 0; t < NSTEP; ++t) {
    const int j0 = spBase + (t * NWAVE + wid) * TILE;
    const int rA = j0 + c, rB = rA + 16;

    // V fragments: independent of S chain -> issue first (overlap)
    f16x8 vf[8];
#pragma unroll
    for (int dt = 0; dt < 8; ++dt)
      vf[dt] = *reinterpret_cast<const f16x8*>(
          VT + (size_t)(dt * 16 + c) * NQ + j0 + 8 * g);

    const f32x4 kk1 = *reinterpret_cast<const f32x4*>(K128 + j0 + 4 * g);
    const f32x4 kk2 = *reinterpret_cast<const f32x4*>(K128 + j0 + 16 + 4 * g);

    // ---- S^T = mfma(K, Q), fp16 ----
    f32x4 s1acc = (f32x4){0.f, 0.f, 0.f, 0.f};
    f32x4 s2acc = (f32x4){0.f, 0.f, 0.f, 0.f};
    const short* KA = Kh + (size_t)rA * 128 + 8 * g;
    const short* KB = Kh + (size_t)rB * 128 + 8 * g;
#pragma unroll
    for (int cc = 0; cc < 4; ++cc)
      s1acc = MF(*reinterpret_cast<const f16x8*>(KA + 32 * cc), qf[cc], s1acc);
#pragma unroll
    for (int cc = 0; cc < 4; ++cc)
      s2acc = MF(*reinterpret_cast<const f16x8*>(KB + 32 * cc), qf[cc], s2acc);

    // ---- finalize S (affine + d=128 rank-1), online softmax ----
    float s1[4], s2[4];
#pragma unroll
    for (int r = 0; r < 4; ++r) {
      s1[r] = (s1acc[r] + q128 * kk1[r]) * sA + sB;
      s2[r] = (s2acc[r] + q128 * kk2[r]) * sA + sB;
    }
    float tmax = fmaxf(fmaxf(fmaxf(s1[0], s1[1]), fmaxf(s1[2], s1[3])),
                       fmaxf(fmaxf(s2[0], s2[1]), fmaxf(s2[2], s2[3])));
    tmax = fmaxf(tmax, __shfl_xor(tmax, 16));
    tmax = fmaxf(tmax, __shfl_xor(tmax, 32));
    const float m_old = m_run;
    const float m_new = fmaxf(m_old, tmax);

    float p1[4], p2[4], tsum = 0.f;
#pragma unroll
    for (int r = 0; r < 4; ++r) {
      p1[r] = __expf(s1[r] - m_new);
      p2[r] = __expf(s2[r] - m_new);
      tsum += p1[r] + p2[r];
    }
    tsum += __shfl_xor(tsum, 16);
    tsum += __shfl_xor(tsum, 32);
    const float alpha = __expf(m_old - m_new);
    l_run = l_run * alpha + tsum;
    m_run = m_new;

    float dp = 0.f;
#pragma unroll
    for (int r = 0; r < 4; ++r) dp += p1[r] * kk1[r] + p2[r] * kk2[r];
    a128 = a128 * alpha + dp;

    if (__any(m_new > m_old)) {     // defer-rescale (alpha==1 for all -> skip)
      float ar[4];
#pragma unroll
      for (int r = 0; r < 4; ++r) ar[r] = __shfl(alpha, 4 * g + r);
#pragma unroll
      for (int dt = 0; dt < 8; ++dt)
#pragma unroll
        for (int r = 0; r < 4; ++r) accO[dt][r] *= ar[r];
    }

    // P fragment: slot e=r -> j=4g+r ; e=4+r -> j=16+4g+r (matches VT perm)
    f16x8 pa;
#pragma unroll
    for (int r = 0; r < 4; ++r) {
      pa[r]     = (_Float16)p1[r];
      pa[4 + r] = (_Float16)p2[r];
    }

    // ---- PV ----
#pragma unroll
    for (int dt = 0; dt < 8; ++dt)
      accO[dt] = MF(pa, vf[dt], accO[dt]);
  }

  // ---- in-block 8-wave merge (proven r5) ----
  a128 += __shfl_xor(a128, 16);
  a128 += __shfl_xor(a128, 32);
  if (lane < 16) mS[wid][lane] = m_run;
  __syncthreads();

  float M = mS[0][c];
#pragma unroll
  for (int w = 1; w < NWAVE; ++w) M = fmaxf(M, mS[w][c]);
  const float ew = __expf(m_run - M);
  if (lane < 16) { lS[wid][lane] = l_run * ew; aS[wid][lane] = a128 * ew; }

  float ewr[4];
#pragma unroll
  for (int r = 0; r < 4; ++r) ewr[r] = __shfl(ew, 4 * g + r);
#pragma unroll
  for (int dt = 0; dt < 8; ++dt)
#pragma unroll
    for (int r = 0; r < 4; ++r) accO[dt][r] *= ewr[r];

  if (wid < 4) {
#pragma unroll
    for (int dt = 0; dt < 8; ++dt)
#pragma unroll
      for (int r = 0; r < 4; ++r)
        OwS[wid][(4 * g + r) * 128 + dt * 16 + c] = accO[dt][r];
  }
  __syncthreads();
  if (wid >= 4) {
#pragma unroll
    for (int dt = 0; dt < 8; ++dt)
#pragma unroll
      for (int r = 0; r < 4; ++r)
        OwS[wid - 4][(4 * g + r) * 128 + dt * 16 + c] += accO[dt][r];
  }
  __syncthreads();

  {
    const int q = tid >> 5, s = tid & 31;
    f32x4 o = *reinterpret_cast<const f32x4*>(&OwS[0][q * 128 + 4 * s]);
#pragma unroll
    for (int i = 1; i < 4; ++i) {
      const f32x4 oi = *reinterpret_cast<const f32x4*>(&OwS[i][q * 128 + 4 * s]);
#pragma unroll
      for (int e = 0; e < 4; ++e) o[e] += oi[e];
    }
    float L = 0.f, A = 0.f, Mq = -INFINITY;
#pragma unroll
    for (int w = 0; w < NWAVE; ++w) {
      L += lS[w][q]; A += aS[w][q]; Mq = fmaxf(Mq, mS[w][q]);
    }
    float* dst = OP + ((size_t)(qg * NSPLIT + sp) * BM + q) * 128 + 4 * s;
    *reinterpret_cast<f32x4*>(dst) = o;
    if (s == 0) {
      float* mla = MLA + (size_t)(qg * NSPLIT + sp) * 48;
      mla[q] = Mq; mla[16 + q] = L; mla[32 + q] = A;
    }
  }

  // ---- atomic ticket (proven r7/r8): last block for this qg merges ----
  __threadfence();                                 // release partials
  __syncthreads();
  if (tid == 0) lastS = (atomicAdd(&cnt[qg], 1) == NSPLIT - 1);
  __syncthreads();
  if (!lastS) return;
  __threadfence();                                 // acquire others' partials

  {
    const int rq = tid >> 5, seg = tid & 31;       // 16 rows x 32 threads (4 cols)
    float mm[NSPLIT];
    float Mq = -INFINITY;
#pragma unroll
    for (int w = 0; w < NSPLIT; ++w) {
      mm[w] = MLA[(size_t)(qg * NSPLIT + w) * 48 + rq];
      Mq = fmaxf(Mq, mm[w]);
    }
    float L = 0.f, A = 0.f;
    float o[4] = {0.f, 0.f, 0.f, 0.f};
#pragma unroll
    for (int w = 0; w < NSPLIT; ++w) {
      const float* mla = MLA + (size_t)(qg * NSPLIT + w) * 48;
      const float eww = __expf(mm[w] - Mq);
      L += eww * mla[16 + rq];
      A += eww * mla[32 + rq];
      const float* Opw = OP + ((size_t)(qg * NSPLIT + w) * BM + rq) * 128 + 4 * seg;
#pragma unroll
      for (int i = 0; i < 4; ++i) o[i] += eww * Opw[i];
    }
    const float invL = 1.0f / L;
#pragma unroll
    for (int i = 0; i < 4; ++i) o[i] *= invL;
    A *= invL;

    // double Lorentz normalization (as reference)
    float part = o[0] * o[0] + o[1] * o[1] + o[2] * o[2] + o[3] * o[3];
    if (seg == 0) part += -2.f * o[0] * o[0] + A * A;   // d0 negated, d128 added
    part += __shfl_xor(part, 1);
    part += __shfl_xor(part, 2);
    part += __shfl_xor(part, 4);
    part += __shfl_xor(part, 8);
    part += __shfl_xor(part, 16);
    const float den1 = sqrtf(fmaxf(fabsf(part), 1e-8f));

    float y[4];
#pragma unroll
    for (int i = 0; i < 4; ++i) y[i] = o[i] / den1;
    const float yA = A / den1;

    float p2 = y[0] * y[0] + y[1] * y[1] + y[2] * y[2] + y[3] * y[3];
    if (seg == 0) p2 += -2.f * y[0] * y[0] + yA * yA;
    p2 += __shfl_xor(p2, 1);
    p2 += __shfl_xor(p2, 2);
    p2 += __shfl_xor(p2, 4);
    p2 += __shfl_xor(p2, 8);
    p2 += __shfl_xor(p2, 16);
    const float den2 = sqrtf(fmaxf(fabsf(p2), 1e-8f));

    float* orow = outg + (size_t)(row0 + rq) * DD;
#pragma unroll
    for (int i = 0; i < 4; ++i) orow[4 * seg + i] = y[i] / den2;
    if (seg == 0) orow[128] = yA / den2;
  }
}

extern "C" void kernel_launch(void* const* d_in, const int* in_sizes, int n_in,
                              void* d_out, int out_size, void* d_ws, size_t ws_size,
                              hipStream_t stream) {
  const float* Qg = (const float*)d_in[0];
  const float* Kg = (const float*)d_in[1];
  const float* sc = (const float*)d_in[2];
  const float* bs = (const float*)d_in[3];
  float* out = (float*)d_out;

  char* ws = (char*)d_ws;
  short* Kh   = (short*)(ws + WS_KH);
  short* VT   = (short*)(ws + WS_VT);
  short* Qh   = (short*)(ws + WS_QH);
  float* K128 = (float*)(ws + WS_K128);
  float* Q128 = (float*)(ws + WS_Q128);
  int*   cnt  = (int*)(ws + WS_CNT);
  float* MLA  = (float*)(ws + WS_MLA);
  float* OP   = (float*)(ws + WS_OP);

  hipMemsetAsync(cnt, 0, NQG * sizeof(int), stream);
  hipLaunchKernelGGL(prepass, dim3(256, 2), dim3(256), 0, stream,
                     Kg, Qg, Kh, Qh, VT, K128, Q128);
  if (ws_size >= NEED(4)) {
    hipLaunchKernelGGL((attn_fused<4>), dim3(NQG * 4), dim3(NT), 0, stream,
                       Qh, Q128, Kh, VT, K128, sc, bs, OP, MLA, cnt, out);
  } else {
    hipLaunchKernelGGL((attn_fused<2>), dim3(NQG * 2), dim3(NT), 0, stream,
                       Qh, Q128, Kh, VT, K128, sc, bs, OP, MLA, cnt, out);
  }
}

// Round 11
// 138.265 us; speedup vs baseline: 3.2545x; 3.2545x over previous
//
#include <hip/hip_runtime.h>
#include <math.h>

// Single-head equivalence (4 identical heads; mean over identical outputs = id).
// Round 11: r5's proven 3-kernel structure (NO device fences anywhere - r10
// showed threadfence wbl2/inv poisons every co-resident block's L2) + per-step
// batched register loads with sched_barrier(0) to expose memory-level
// parallelism (r5 at VGPR=64 serialized ~18 loads/step at ~1.2k cy each).
//   prepass:    K,Q -> fp16 planes (Kh row, VT transposed+slot-permuted, Qh row
//               with d0 negated) + dense fp32 K128/Q128 columns.
//   attn_split: 16 queries/block, 8 waves split a KV half, NSPLIT=2,
//               XCD-pinned. Per step: load ALL V/K/K128 into named registers,
//               sched_barrier, then compute. launch_bounds(512,2) - cap 256,
//               no strangle (r7), no cross-step buffering (r9 spill lesson).
//   merge_norm: combine 2 splits + double Lorentz normalization.

typedef __attribute__((ext_vector_type(8))) _Float16 f16x8;
typedef __attribute__((ext_vector_type(8))) short short8;
typedef __attribute__((ext_vector_type(4))) float f32x4;

#define NQ 4096
#define DD 129
#define BM 16
#define NWAVE 8
#define NT 512
#define TILE 32
#define NSPLIT 2
#define KVSEG (NQ / NSPLIT)                 // 2048
#define NSTEP (KVSEG / (NWAVE * TILE))      // 8
#define NQG (NQ / BM)                       // 256

// d_ws byte offsets (total 8 MB - bound proven available in r5/r8/r10)
#define WS_KH   ((size_t)0)                        // NQ*128 fp16 = 1 MB
#define WS_VT   ((size_t)1 << 20)                  // 128*NQ fp16 = 1 MB
#define WS_QH   ((size_t)2 << 20)                  // NQ*128 fp16 = 1 MB
#define WS_K128 ((size_t)3 << 20)                  // NQ fp32 = 16 KB
#define WS_Q128 (((size_t)3 << 20) + (16 << 10))   // NQ fp32 = 16 KB
#define WS_MLA  (((size_t)3 << 20) + (32 << 10))   // NQG*2*48 f32 = 96 KB
#define WS_OP   ((size_t)4 << 20)                  // NQG*2*16*128 f32 = 4 MB

__device__ __forceinline__ short f2h_bits(float x) {
  _Float16 h = (_Float16)x;
  return *reinterpret_cast<short*>(&h);
}

#define MF(a, b, cacc) __builtin_amdgcn_mfma_f32_16x16x32_f16(a, b, cacc, 0, 0, 0)

// ---------------- prepass (proven rounds 6-10, unchanged) --------------------
__global__ __launch_bounds__(256) void prepass(
    const float* __restrict__ Kg, const float* __restrict__ Qg,
    short* __restrict__ Kh, short* __restrict__ Qh, short* __restrict__ VT,
    float* __restrict__ K128, float* __restrict__ Q128)
{
  __shared__ short tile[32][72];
  const int bx  = blockIdx.x;
  const int isQ = blockIdx.y;
  const int jg = bx >> 1, dh = bx & 1;
  const int j0 = jg * 32, d0 = dh * 64;
  const float* src = isQ ? Qg : Kg;
  short* plane = isQ ? Qh : Kh;

  const int t  = threadIdx.x;
  const int r  = t >> 3;
  const int e0 = (t & 7) * 8;

  {
    const float* s = src + (size_t)(j0 + r) * DD + d0 + e0;
    short8 sv;
#pragma unroll
    for (int e = 0; e < 8; ++e) {
      float v = s[e];
      if (isQ && dh == 0 && e0 == 0 && e == 0) v = -v;   // Lorentz time coord
      sv[e] = f2h_bits(v);
    }
    *reinterpret_cast<short8*>(&tile[r][e0]) = sv;
    *reinterpret_cast<short8*>(plane + (size_t)(j0 + r) * 128 + d0 + e0) = sv;
  }
  if (dh == 0 && t < 32) {
    const float v = src[(size_t)(j0 + t) * DD + 128];
    (isQ ? Q128 : K128)[j0 + t] = v;
  }
  if (isQ) return;
  __syncthreads();

  // transposed + k-slot-permuted plane (slot p=8g+e <-> j: e<4->4g+e else 16+4g+e-4)
  {
    const int dl = t >> 2, q8 = t & 3;
    short8 sv;
#pragma unroll
    for (int e = 0; e < 8; ++e) {
      const int j = (e < 4) ? (4 * q8 + e) : (16 + 4 * q8 + (e - 4));
      sv[e] = tile[j][dl];
    }
    *reinterpret_cast<short8*>(VT + (size_t)(d0 + dl) * NQ + j0 + q8 * 8) = sv;
  }
}

// ---------------- flash attention, one KV half per block ---------------------
__global__ __launch_bounds__(NT, 2) void attn_split(
    const short* __restrict__ Qh, const float* __restrict__ Q128,
    const short* __restrict__ Kh, const short* __restrict__ VT,
    const float* __restrict__ K128,
    const float* __restrict__ scale_p, const float* __restrict__ bias_p,
    float* __restrict__ OP, float* __restrict__ MLA)
{
  __shared__ float OwS[4][BM * 128];
  __shared__ float mS[NWAVE][BM], lS[NWAVE][BM], aS[NWAVE][BM];

  // XCD-pinned bijection (proven r5): blocks on one XCD share sp.
  const int bid = blockIdx.x;               // 0..511
  const int xcd = bid & 7;
  const int sp  = xcd & 1;
  const int qg  = ((xcd >> 1) << 6) + (bid >> 3);   // 0..255
  const int spBase = sp * KVSEG;

  const int tid  = threadIdx.x;
  const int wid  = tid >> 6;
  const int lane = tid & 63;
  const int g    = lane >> 4;   // 0..3
  const int c    = lane & 15;   // 0..15
  const int row0 = qg * BM;

  const float sA = 2.0f / scale_p[0];
  const float sB = sA + bias_p[0];          // S = dot*sA + sB

  const int qrow = row0 + c;
  f16x8 qf[4];
#pragma unroll
  for (int cc = 0; cc < 4; ++cc)
    qf[cc] = *reinterpret_cast<const f16x8*>(Qh + (size_t)qrow * 128 + 32 * cc + 8 * g);
  const float q128 = Q128[qrow];

  f32x4 accO[8];
#pragma unroll
  for (int i = 0; i < 8; ++i) accO[i] = (f32x4){0.f, 0.f, 0.f, 0.f};
  float m_run = -INFINITY, l_run = 0.f, a128 = 0.f;

  for (int t = 0; t < NSTEP; ++t) {
    const int j0 = spBase + (t * NWAVE + wid) * TILE;

    // ---- batch-issue ALL of this step's loads (V, K, K128) ----
    f16x8 vf[8], ka[4], kb[4];
#pragma unroll
    for (int dt = 0; dt < 8; ++dt)
      vf[dt] = *reinterpret_cast<const f16x8*>(
          VT + (size_t)(dt * 16 + c) * NQ + j0 + 8 * g);
    const short* KA = Kh + (size_t)(j0 + c) * 128 + 8 * g;
    const short* KB = Kh + (size_t)(j0 + 16 + c) * 128 + 8 * g;
#pragma unroll
    for (int cc = 0; cc < 4; ++cc) {
      ka[cc] = *reinterpret_cast<const f16x8*>(KA + 32 * cc);
      kb[cc] = *reinterpret_cast<const f16x8*>(KB + 32 * cc);
    }
    const f32x4 kk1 = *reinterpret_cast<const f32x4*>(K128 + j0 + 4 * g);
    const f32x4 kk2 = *reinterpret_cast<const f32x4*>(K128 + j0 + 16 + 4 * g);
    __builtin_amdgcn_sched_barrier(0);   // loads above, compute below

    // ---- S^T = mfma(K, Q), fp16 ----
    f32x4 s1acc = (f32x4){0.f, 0.f, 0.f, 0.f};
    f32x4 s2acc = (f32x4){0.f, 0.f, 0.f, 0.f};
#pragma unroll
    for (int cc = 0; cc < 4; ++cc) s1acc = MF(ka[cc], qf[cc], s1acc);
#pragma unroll
    for (int cc = 0; cc < 4; ++cc) s2acc = MF(kb[cc], qf[cc], s2acc);

    // ---- finalize S (affine + d=128 rank-1), online softmax ----
    float s1[4], s2[4];
#pragma unroll
    for (int r = 0; r < 4; ++r) {
      s1[r] = (s1acc[r] + q128 * kk1[r]) * sA + sB;
      s2[r] = (s2acc[r] + q128 * kk2[r]) * sA + sB;
    }
    float tmax = fmaxf(fmaxf(fmaxf(s1[0], s1[1]), fmaxf(s1[2], s1[3])),
                       fmaxf(fmaxf(s2[0], s2[1]), fmaxf(s2[2], s2[3])));
    tmax = fmaxf(tmax, __shfl_xor(tmax, 16));
    tmax = fmaxf(tmax, __shfl_xor(tmax, 32));
    const float m_old = m_run;
    const float m_new = fmaxf(m_old, tmax);

    float p1[4], p2[4], tsum = 0.f;
#pragma unroll
    for (int r = 0; r < 4; ++r) {
      p1[r] = __expf(s1[r] - m_new);
      p2[r] = __expf(s2[r] - m_new);
      tsum += p1[r] + p2[r];
    }
    tsum += __shfl_xor(tsum, 16);
    tsum += __shfl_xor(tsum, 32);
    const float alpha = __expf(m_old - m_new);
    l_run = l_run * alpha + tsum;
    m_run = m_new;

    float dp = 0.f;
#pragma unroll
    for (int r = 0; r < 4; ++r) dp += p1[r] * kk1[r] + p2[r] * kk2[r];
    a128 = a128 * alpha + dp;

    if (__any(m_new > m_old)) {     // defer-rescale (alpha==1 for all -> skip)
      float ar[4];
#pragma unroll
      for (int r = 0; r < 4; ++r) ar[r] = __shfl(alpha, 4 * g + r);
#pragma unroll
      for (int dt = 0; dt < 8; ++dt)
#pragma unroll
        for (int r = 0; r < 4; ++r) accO[dt][r] *= ar[r];
    }

    // P fragment: slot e=r -> j=4g+r ; e=4+r -> j=16+4g+r (matches VT perm)
    f16x8 pa;
#pragma unroll
    for (int r = 0; r < 4; ++r) {
      pa[r]     = (_Float16)p1[r];
      pa[4 + r] = (_Float16)p2[r];
    }

    // ---- PV ----
#pragma unroll
    for (int dt = 0; dt < 8; ++dt)
      accO[dt] = MF(pa, vf[dt], accO[dt]);
  }

  // ---- in-block 8-wave merge (proven r5) ----
  a128 += __shfl_xor(a128, 16);
  a128 += __shfl_xor(a128, 32);
  if (lane < 16) mS[wid][lane] = m_run;
  __syncthreads();

  float M = mS[0][c];
#pragma unroll
  for (int w = 1; w < NWAVE; ++w) M = fmaxf(M, mS[w][c]);
  const float ew = __expf(m_run - M);
  if (lane < 16) { lS[wid][lane] = l_run * ew; aS[wid][lane] = a128 * ew; }

  float ewr[4];
#pragma unroll
  for (int r = 0; r < 4; ++r) ewr[r] = __shfl(ew, 4 * g + r);
#pragma unroll
  for (int dt = 0; dt < 8; ++dt)
#pragma unroll
    for (int r = 0; r < 4; ++r) accO[dt][r] *= ewr[r];

  if (wid < 4) {
#pragma unroll
    for (int dt = 0; dt < 8; ++dt)
#pragma unroll
      for (int r = 0; r < 4; ++r)
        OwS[wid][(4 * g + r) * 128 + dt * 16 + c] = accO[dt][r];
  }
  __syncthreads();
  if (wid >= 4) {
#pragma unroll
    for (int dt = 0; dt < 8; ++dt)
#pragma unroll
      for (int r = 0; r < 4; ++r)
        OwS[wid - 4][(4 * g + r) * 128 + dt * 16 + c] += accO[dt][r];
  }
  __syncthreads();

  {
    const int q = tid >> 5, s = tid & 31;
    f32x4 o = *reinterpret_cast<const f32x4*>(&OwS[0][q * 128 + 4 * s]);
#pragma unroll
    for (int i = 1; i < 4; ++i) {
      const f32x4 oi = *reinterpret_cast<const f32x4*>(&OwS[i][q * 128 + 4 * s]);
#pragma unroll
      for (int e = 0; e < 4; ++e) o[e] += oi[e];
    }
    float L = 0.f, A = 0.f, Mq = -INFINITY;
#pragma unroll
    for (int w = 0; w < NWAVE; ++w) {
      L += lS[w][q]; A += aS[w][q]; Mq = fmaxf(Mq, mS[w][q]);
    }
    float* dst = OP + ((size_t)(qg * NSPLIT + sp) * BM + q) * 128 + 4 * s;
    *reinterpret_cast<f32x4*>(dst) = o;
    if (s == 0) {
      float* mla = MLA + (size_t)(qg * NSPLIT + sp) * 48;
      mla[q] = Mq; mla[16 + q] = L; mla[32 + q] = A;
    }
  }
}

// ---------------- merge splits + double Lorentz normalization (proven r5) ----
__global__ __launch_bounds__(256) void merge_norm(
    const float* __restrict__ OP, const float* __restrict__ MLA,
    float* __restrict__ outg)
{
  const int qg  = blockIdx.x;
  const int rq  = threadIdx.x >> 4;   // 0..15
  const int seg = threadIdx.x & 15;   // 8 d-cols each

  const float* a0 = MLA + (size_t)(qg * NSPLIT + 0) * 48;
  const float* a1 = MLA + (size_t)(qg * NSPLIT + 1) * 48;
  const float m1 = a0[rq], l1 = a0[16 + rq], A1 = a0[32 + rq];
  const float m2 = a1[rq], l2 = a1[16 + rq], A2 = a1[32 + rq];
  const float M  = fmaxf(m1, m2);
  const float w1 = __expf(m1 - M), w2 = __expf(m2 - M);
  const float invL = 1.0f / (w1 * l1 + w2 * l2);

  const float* O1 = OP + ((size_t)(qg * NSPLIT + 0) * BM + rq) * 128 + 8 * seg;
  const float* O2 = OP + ((size_t)(qg * NSPLIT + 1) * BM + rq) * 128 + 8 * seg;
  float o[8];
#pragma unroll
  for (int i = 0; i < 8; ++i) o[i] = (w1 * O1[i] + w2 * O2[i]) * invL;
  const float A = (w1 * A1 + w2 * A2) * invL;

  float part = 0.f;
#pragma unroll
  for (int i = 0; i < 8; ++i) part += o[i] * o[i];
  if (seg == 0) part += -2.f * o[0] * o[0] + A * A;   // d0 negated, d128 added
  part += __shfl_xor(part, 1);
  part += __shfl_xor(part, 2);
  part += __shfl_xor(part, 4);
  part += __shfl_xor(part, 8);
  const float den1 = sqrtf(fmaxf(fabsf(part), 1e-8f));

  float y[8];
#pragma unroll
  for (int i = 0; i < 8; ++i) y[i] = o[i] / den1;
  const float yA = A / den1;

  float p2 = 0.f;
#pragma unroll
  for (int i = 0; i < 8; ++i) p2 += y[i] * y[i];
  if (seg == 0) p2 += -2.f * y[0] * y[0] + yA * yA;
  p2 += __shfl_xor(p2, 1);
  p2 += __shfl_xor(p2, 2);
  p2 += __shfl_xor(p2, 4);
  p2 += __shfl_xor(p2, 8);
  const float den2 = sqrtf(fmaxf(fabsf(p2), 1e-8f));

  float* orow = outg + (size_t)(qg * BM + rq) * DD;
#pragma unroll
  for (int i = 0; i < 8; ++i) orow[8 * seg + i] = y[i] / den2;
  if (seg == 0) orow[128] = yA / den2;
}

extern "C" void kernel_launch(void* const* d_in, const int* in_sizes, int n_in,
                              void* d_out, int out_size, void* d_ws, size_t ws_size,
                              hipStream_t stream) {
  const float* Qg = (const float*)d_in[0];
  const float* Kg = (const float*)d_in[1];
  const float* sc = (const float*)d_in[2];
  const float* bs = (const float*)d_in[3];
  float* out = (float*)d_out;

  char* ws = (char*)d_ws;
  short* Kh   = (short*)(ws + WS_KH);
  short* VT   = (short*)(ws + WS_VT);
  short* Qh   = (short*)(ws + WS_QH);
  float* K128 = (float*)(ws + WS_K128);
  float* Q128 = (float*)(ws + WS_Q128);
  float* MLA  = (float*)(ws + WS_MLA);
  float* OP   = (float*)(ws + WS_OP);

  hipLaunchKernelGGL(prepass, dim3(256, 2), dim3(256), 0, stream,
                     Kg, Qg, Kh, Qh, VT, K128, Q128);
  hipLaunchKernelGGL(attn_split, dim3(NQG * NSPLIT), dim3(NT), 0, stream,
                     Qh, Q128, Kh, VT, K128, sc, bs, OP, MLA);
  hipLaunchKernelGGL(merge_norm, dim3(NQG), dim3(256), 0, stream, OP, MLA, out);
}